// Round 2
// baseline (380.389 us; speedup 1.0000x reference)
//
#include <hip/hip_runtime.h>
#include <hip/hip_bf16.h>

typedef __hip_bfloat16 bf16;

#define B_    32
#define D_    512
#define HID_  256
#define NF_   8
#define CIN_  64
#define COUT_ 64
#define HW_   64
#define CONV_OUT_ELEMS (B_ * COUT_ * HW_ * HW_)   // 8388608

__device__ inline float b2f(bf16 v) { return __bfloat162float(v); }
__device__ inline bf16  f2b(float f) { return __float2bfloat16(f); }

// ---------------------------------------------------------------------------
// Data-driven dtype detection: returns 1 if buffer looks like bf16, 0 if fp32.
// Low 16 bits of each sampled 32-bit word: for genuine bf16 data these are a
// bf16 element with a sane exponent; for fp32 data they are random mantissa
// bits (sane with p=0.5 per word -> all-32-sane with p=2^-32).
// All-zero buffers classify as bf16; zeros read identically either way.
// ---------------------------------------------------------------------------
__device__ inline int detect_bf16(const void* p, int elems) {
    const unsigned* w = (const unsigned*)p;
    int nw = elems >> 1;           // words safely readable under bf16 layout
    if (nw < 1) return 1;
    int n = nw < 32 ? nw : 32;
    int step = nw / n;
    int ok = 1;
    for (int k = 0; k < n; ++k) {
        unsigned v = w[k * step];
        unsigned lo = v & 0xFFFFu;
        unsigned ex = (lo >> 7) & 0xFFu;
        if (!(lo == 0u || (ex >= 64u && ex <= 191u))) ok = 0;
    }
    return ok;
}

__device__ inline float ldf(const void* p, int i, int isbf) {
    return isbf ? __bfloat162float(((const bf16*)p)[i]) : ((const float*)p)[i];
}

// ---------------------------------------------------------------------------
// Kernel 1: routing MLP + softmax + agg bias.  grid=32 (one block per sample)
// ---------------------------------------------------------------------------
__global__ __launch_bounds__(256) void routing_kernel(
    const void* __restrict__ x,      // [32,512]
    const void* __restrict__ xin,    // [32,64,64,64] (only for out-dtype probe)
    const void* __restrict__ fc1_w,  // [256,512]
    const void* __restrict__ fc1_b,  // [256]
    const void* __restrict__ fc2_w,  // [8,256]
    const void* __restrict__ fc2_b,  // [8]
    const void* __restrict__ bias_p, // [8,64]
    float* __restrict__ ws_attn,     // [32,8]
    float* __restrict__ ws_aggb,     // [32,64]
    void* __restrict__ d_out)        // attn tail at elem offset CONV_OUT_ELEMS
{
    __shared__ float xs[D_];
    __shared__ float hs[HID_];
    __shared__ float at[NF_];
    __shared__ int   fl[7];
    const int b = blockIdx.x;
    const int t = threadIdx.x;

    if (t == 0) {
        fl[0] = detect_bf16(x,      B_ * D_);
        fl[1] = detect_bf16(fc1_w,  HID_ * D_);
        fl[2] = detect_bf16(fc1_b,  HID_);
        fl[3] = detect_bf16(fc2_w,  NF_ * HID_);
        fl[4] = detect_bf16(fc2_b,  NF_);
        fl[5] = detect_bf16(bias_p, NF_ * COUT_);
        fl[6] = detect_bf16(xin,    B_ * CIN_ * HW_ * HW_);  // out dtype proxy
    }
    __syncthreads();

    for (int i = t; i < D_; i += 256) xs[i] = ldf(x, b * D_ + i, fl[0]);
    __syncthreads();

    // h[t] = relu(x . fc1_w[t] + fc1_b[t])
    {
        float s = 0.f;
        const int base = t * D_;
        const int wbf = fl[1];
#pragma unroll 8
        for (int i = 0; i < D_; ++i) s += xs[i] * ldf(fc1_w, base + i, wbf);
        s += ldf(fc1_b, t, fl[2]);
        hs[t] = s > 0.f ? s : 0.f;
    }
    __syncthreads();

    if (t < NF_) {
        float s = ldf(fc2_b, t, fl[4]);
        const int base = t * HID_;
        for (int j = 0; j < HID_; ++j) s += hs[j] * ldf(fc2_w, base + j, fl[3]);
        at[t] = s * (1.0f / 30.0f);   // logits / TEMPERATURE
    }
    __syncthreads();
    if (t == 0) {
        float m = at[0];
#pragma unroll
        for (int f = 1; f < NF_; ++f) m = fmaxf(m, at[f]);
        float e[NF_], ssum = 0.f;
#pragma unroll
        for (int f = 0; f < NF_; ++f) { e[f] = __expf(at[f] - m); ssum += e[f]; }
        float inv = 1.0f / ssum;
#pragma unroll
        for (int f = 0; f < NF_; ++f) at[f] = e[f] * inv;
    }
    __syncthreads();
    if (t < NF_) {
        ws_attn[b * NF_ + t] = at[t];
        if (fl[6]) ((bf16*)d_out)[CONV_OUT_ELEMS + b * NF_ + t] = f2b(at[t]);
        else      ((float*)d_out)[CONV_OUT_ELEMS + b * NF_ + t] = at[t];
    }
    if (t < COUT_) {
        float s = 0.f;
#pragma unroll
        for (int f = 0; f < NF_; ++f) s += at[f] * ldf(bias_p, f * COUT_ + t, fl[5]);
        ws_aggb[b * COUT_ + t] = s;
    }
}

// ---------------------------------------------------------------------------
// Kernel 2: agg_w[b, r] = sum_f attn[b,f] * weight[f, r]   r in [0, 36864)
// grid = 32 * 144 = 4608 blocks of 256 (144*256 == 36864 exactly)
// ---------------------------------------------------------------------------
__global__ __launch_bounds__(256) void agg_kernel(
    const void* __restrict__ weight,   // [8, 36864]
    const float* __restrict__ ws_attn, // [32, 8]
    float* __restrict__ ws_aggw)       // [32, 36864]
{
    __shared__ int fl;
    if (threadIdx.x == 0) fl = detect_bf16(weight, NF_ * 36864);
    __syncthreads();
    const int blk = blockIdx.x;
    const int b = blk / 144;
    const int r = (blk % 144) * 256 + threadIdx.x;
    float s = 0.f;
#pragma unroll
    for (int f = 0; f < NF_; ++f)
        s += ws_attn[b * NF_ + f] * ldf(weight, f * 36864 + r, fl);
    ws_aggw[b * 36864 + r] = s;
}

// ---------------------------------------------------------------------------
// Kernel 3: per-sample 3x3 conv, pad=1.
// Block: sample b, 32 couts (blockIdx.y), 4 output rows (blockIdx.x), 64 cols.
// cin chunked by 16; input halo + weights staged in LDS.
// ---------------------------------------------------------------------------
__global__ __launch_bounds__(256) void conv_kernel(
    const void* __restrict__ xin,     // [32,64,64,64]
    const float* __restrict__ aggw,   // [32,64,576]  (o, cin, kh, kw)
    const float* __restrict__ aggb,   // [32,64]
    void* __restrict__ out)           // [32,64,64,64] + attn tail
{
    __shared__ __align__(16) float in_s[16][6][66];
    __shared__ __align__(16) float w_s[16][32][12];
    __shared__ int s_bf;

    const int t     = threadIdx.x;
    const int y0    = blockIdx.x * 4;
    const int o0    = blockIdx.y * 32;
    const int b     = blockIdx.z;
    const int xcol  = t & 63;
    const int obase = (t >> 6) * 8;

    if (t == 0) s_bf = detect_bf16(xin, B_ * CIN_ * HW_ * HW_);

    float acc[8][4];
#pragma unroll
    for (int oo = 0; oo < 8; ++oo)
#pragma unroll
        for (int ry = 0; ry < 4; ++ry) acc[oo][ry] = 0.f;

    for (int cc = 0; cc < 4; ++cc) {
        __syncthreads();
        const int inbf = s_bf;
        // stage weights: 32 couts x 16 cin x 9 taps
        for (int i = t; i < 32 * 16 * 9; i += 256) {
            const int o = i / 144, rem = i % 144;
            const int ci = rem / 9, k = rem % 9;
            w_s[ci][o][k] = aggw[(b * 64 + o0 + o) * 576 + (cc * 16 + ci) * 9 + k];
        }
        // stage input halo: 16 cin x 6 rows x 66 cols (zero-padded borders)
        for (int i = t; i < 16 * 6 * 66; i += 256) {
            const int ci = i / 396, rem = i % 396;
            const int rr = rem / 66, c = rem % 66;
            const int gy = y0 - 1 + rr, gx = c - 1;
            float v = 0.f;
            if (gy >= 0 && gy < HW_ && gx >= 0 && gx < HW_)
                v = ldf(xin, ((b * CIN_ + cc * 16 + ci) * HW_ + gy) * HW_ + gx, inbf);
            in_s[ci][rr][c] = v;
        }
        __syncthreads();

        for (int ci = 0; ci < 16; ++ci) {
            float iv[6][3];
#pragma unroll
            for (int rr = 0; rr < 6; ++rr)
#pragma unroll
                for (int kw = 0; kw < 3; ++kw) iv[rr][kw] = in_s[ci][rr][xcol + kw];
#pragma unroll
            for (int oo = 0; oo < 8; ++oo) {
                const float4 w0 = *(const float4*)&w_s[ci][obase + oo][0];
                const float4 w1 = *(const float4*)&w_s[ci][obase + oo][4];
                const float  w8 = w_s[ci][obase + oo][8];
#pragma unroll
                for (int ry = 0; ry < 4; ++ry) {
                    float a = acc[oo][ry];
                    a = fmaf(w0.x, iv[ry + 0][0], a);
                    a = fmaf(w0.y, iv[ry + 0][1], a);
                    a = fmaf(w0.z, iv[ry + 0][2], a);
                    a = fmaf(w0.w, iv[ry + 1][0], a);
                    a = fmaf(w1.x, iv[ry + 1][1], a);
                    a = fmaf(w1.y, iv[ry + 1][2], a);
                    a = fmaf(w1.z, iv[ry + 2][0], a);
                    a = fmaf(w1.w, iv[ry + 2][1], a);
                    a = fmaf(w8,   iv[ry + 2][2], a);
                    acc[oo][ry] = a;
                }
            }
        }
    }

    // epilogue: + per-(b,o) bias, write in detected output dtype
    const int outbf = s_bf;
#pragma unroll
    for (int oo = 0; oo < 8; ++oo) {
        const int o = o0 + obase + oo;
        const float bias = aggb[b * COUT_ + o];
#pragma unroll
        for (int ry = 0; ry < 4; ++ry) {
            const int idx = ((b * COUT_ + o) * HW_ + (y0 + ry)) * HW_ + xcol;
            const float v = acc[oo][ry] + bias;
            if (outbf) ((bf16*)out)[idx] = f2b(v);
            else      ((float*)out)[idx] = v;
        }
    }
}

// ---------------------------------------------------------------------------
extern "C" void kernel_launch(void* const* d_in, const int* in_sizes, int n_in,
                              void* d_out, int out_size, void* d_ws, size_t ws_size,
                              hipStream_t stream) {
    const void* x      = d_in[0]; // [32,512]
    const void* xin    = d_in[1]; // [32,64,64,64]
    const void* fc1_w  = d_in[2]; // [256,512]
    const void* fc1_b  = d_in[3]; // [256]
    const void* fc2_w  = d_in[4]; // [8,256]
    const void* fc2_b  = d_in[5]; // [8]
    const void* weight = d_in[6]; // [8,64,64,3,3]
    const void* bias_p = d_in[7]; // [8,64]

    float* ws      = (float*)d_ws;
    float* ws_attn = ws;            // 256 floats
    float* ws_aggb = ws + 256;      // 2048 floats
    float* ws_aggw = ws + 2304;     // 1,179,648 floats (~4.7 MB total)

    routing_kernel<<<dim3(B_), dim3(256), 0, stream>>>(
        x, xin, fc1_w, fc1_b, fc2_w, fc2_b, bias_p, ws_attn, ws_aggb, d_out);

    agg_kernel<<<dim3(B_ * 144), dim3(256), 0, stream>>>(weight, ws_attn, ws_aggw);

    conv_kernel<<<dim3(16, 2, B_), dim3(256), 0, stream>>>(xin, ws_aggw, ws_aggb, d_out);
}

// Round 3
// 159.331 us; speedup vs baseline: 2.3874x; 2.3874x over previous
//
#include <hip/hip_runtime.h>
#include <hip/hip_bf16.h>

typedef __hip_bfloat16 bf16;
typedef unsigned short u16;
typedef unsigned int   u32;

#define B_    32
#define D_    512
#define HID_  256
#define NF_   8
#define CIN_  64
#define COUT_ 64
#define HW_   64
#define CONV_OUT_ELEMS (B_ * COUT_ * HW_ * HW_)   // 8388608
#define WBANK_ (NF_ * 36864)                       // weight elems

typedef __attribute__((ext_vector_type(8))) short  short8;   // 8 bf16 = 4 VGPRs (MFMA A/B frag)
typedef __attribute__((ext_vector_type(4))) float  floatx4;  // MFMA C/D frag

__device__ inline float b2f(bf16 v) { return __bfloat162float(v); }
__device__ inline bf16  f2b(float f) { return __float2bfloat16(f); }
__device__ inline u16 f2bu(float f) { union { bf16 h; u16 u; } c; c.h = __float2bfloat16(f); return c.u; }
__device__ inline float bu2f(u16 u) { union { u32 i; float f; } c; c.i = ((u32)u) << 16; return c.f; }

// dtype sniff: 1 if buffer decodes as bf16 (low16 of sampled words = sane bf16), else 0 (fp32)
__device__ inline int detect_bf16(const void* p, int elems) {
    const u32* w = (const u32*)p;
    int nw = elems >> 1;
    if (nw < 1) return 1;
    int n = nw < 32 ? nw : 32;
    int step = nw / n;
    int ok = 1;
#pragma unroll 8
    for (int k = 0; k < n; ++k) {
        u32 v = w[k * step];
        u32 lo = v & 0xFFFFu;
        u32 ex = (lo >> 7) & 0xFFu;
        if (!(lo == 0u || (ex >= 64u && ex <= 191u))) ok = 0;
    }
    return ok;
}

__device__ inline float ldf(const void* p, int i, int isbf) {
    return isbf ? __bfloat162float(((const bf16*)p)[i]) : ((const float*)p)[i];
}

// ---------------------------------------------------------------------------
// Kernel 1: routing MLP + softmax + agg bias.  grid=32
// ---------------------------------------------------------------------------
__global__ __launch_bounds__(256) void routing_kernel(
    const void* __restrict__ x, const void* __restrict__ xin,
    const void* __restrict__ fc1_w, const void* __restrict__ fc1_b,
    const void* __restrict__ fc2_w, const void* __restrict__ fc2_b,
    const void* __restrict__ bias_p,
    float* __restrict__ ws_attn, float* __restrict__ ws_aggb,
    void* __restrict__ d_out)
{
    __shared__ float xs[D_];
    __shared__ float hs[HID_];
    __shared__ float at[NF_];
    __shared__ int   fl[7];
    const int b = blockIdx.x;
    const int t = threadIdx.x;

    if (t == 0) {
        fl[0] = detect_bf16(x,      B_ * D_);
        fl[1] = detect_bf16(fc1_w,  HID_ * D_);
        fl[2] = detect_bf16(fc1_b,  HID_);
        fl[3] = detect_bf16(fc2_w,  NF_ * HID_);
        fl[4] = detect_bf16(fc2_b,  NF_);
        fl[5] = detect_bf16(bias_p, NF_ * COUT_);
        fl[6] = detect_bf16(xin,    B_ * CIN_ * HW_ * HW_);   // output dtype proxy
    }
    __syncthreads();

    for (int i = t; i < D_; i += 256) xs[i] = ldf(x, b * D_ + i, fl[0]);
    __syncthreads();

    // h[t] = relu(x . fc1_w[t] + fc1_b[t]) — vectorized per dtype
    {
        float s = 0.f;
        if (fl[1]) {
            const uint4* row = (const uint4*)((const bf16*)fc1_w + t * D_);
#pragma unroll 4
            for (int i = 0; i < D_ / 8; ++i) {
                uint4 u = row[i];
                const float* xp = xs + i * 8;
                s += bu2f((u16)(u.x & 0xFFFF)) * xp[0] + bu2f((u16)(u.x >> 16)) * xp[1]
                   + bu2f((u16)(u.y & 0xFFFF)) * xp[2] + bu2f((u16)(u.y >> 16)) * xp[3]
                   + bu2f((u16)(u.z & 0xFFFF)) * xp[4] + bu2f((u16)(u.z >> 16)) * xp[5]
                   + bu2f((u16)(u.w & 0xFFFF)) * xp[6] + bu2f((u16)(u.w >> 16)) * xp[7];
            }
        } else {
            const float4* row = (const float4*)((const float*)fc1_w + t * D_);
#pragma unroll 4
            for (int i = 0; i < D_ / 4; ++i) {
                float4 u = row[i];
                const float* xp = xs + i * 4;
                s += u.x * xp[0] + u.y * xp[1] + u.z * xp[2] + u.w * xp[3];
            }
        }
        s += ldf(fc1_b, t, fl[2]);
        hs[t] = s > 0.f ? s : 0.f;
    }
    __syncthreads();

    if (t < NF_) {
        float s = ldf(fc2_b, t, fl[4]);
        const int base = t * HID_;
        for (int j = 0; j < HID_; ++j) s += hs[j] * ldf(fc2_w, base + j, fl[3]);
        at[t] = s * (1.0f / 30.0f);
    }
    __syncthreads();
    if (t == 0) {
        float m = at[0];
#pragma unroll
        for (int f = 1; f < NF_; ++f) m = fmaxf(m, at[f]);
        float e[NF_], ssum = 0.f;
#pragma unroll
        for (int f = 0; f < NF_; ++f) { e[f] = __expf(at[f] - m); ssum += e[f]; }
        float inv = 1.0f / ssum;
#pragma unroll
        for (int f = 0; f < NF_; ++f) at[f] = e[f] * inv;
    }
    __syncthreads();
    if (t < NF_) {
        ws_attn[b * NF_ + t] = at[t];
        if (fl[6]) ((bf16*)d_out)[CONV_OUT_ELEMS + b * NF_ + t] = f2b(at[t]);
        else      ((float*)d_out)[CONV_OUT_ELEMS + b * NF_ + t] = at[t];
    }
    if (t < COUT_) {
        float s = 0.f;
#pragma unroll
        for (int f = 0; f < NF_; ++f) s += at[f] * ldf(bias_p, f * COUT_ + t, fl[5]);
        ws_aggb[b * COUT_ + t] = s;
    }
}

// ---------------------------------------------------------------------------
// Kernel 2: aggregate kernel bank -> bf16 in MFMA layout [b][tap][o][ci].
// grid = 32 samples * 16 o-quads = 512 blocks, 256 threads.
// ---------------------------------------------------------------------------
__global__ __launch_bounds__(256) void agg_kernel(
    const void* __restrict__ weight,   // [8][64][64][3][3]
    const float* __restrict__ ws_attn, // [32][8]
    u16* __restrict__ aggw)            // [32][9][64][64] bf16
{
    __shared__ float lds[2304];        // [o_l(4)][ci(64)][tap(9)]
    __shared__ float s_at[NF_];
    __shared__ int   s_wbf;
    const int t  = threadIdx.x;
    const int b  = blockIdx.x >> 4;
    const int o0 = (blockIdx.x & 15) * 4;

    if (t == 0) s_wbf = detect_bf16(weight, WBANK_);
    if (t < NF_) s_at[t] = ws_attn[b * NF_ + t];
    __syncthreads();
    const int wbf = s_wbf;

#pragma unroll
    for (int j = 0; j < 9; ++j) {
        const int flat = t + 256 * j;              // < 2304
        const int o_l = flat / 576, rr = flat - o_l * 576;  // rr = ci*9+tap
        const int gbase = (o0 + o_l) * 576 + rr;
        float s = 0.f;
        if (wbf) {
#pragma unroll
            for (int f = 0; f < NF_; ++f) s += s_at[f] * b2f(((const bf16*)weight)[f * 36864 + gbase]);
        } else {
#pragma unroll
            for (int f = 0; f < NF_; ++f) s += s_at[f] * ((const float*)weight)[f * 36864 + gbase];
        }
        lds[flat] = s;
    }
    __syncthreads();
#pragma unroll
    for (int j = 0; j < 9; ++j) {
        const int e = t + 256 * j;                 // tap(9) x o_l(4) x ci(64)
        const int tap = e >> 8, o_l = (e >> 6) & 3, ci = e & 63;
        aggw[b * 36864 + tap * 4096 + (o0 + o_l) * 64 + ci] = f2bu(lds[o_l * 576 + ci * 9 + tap]);
    }
}

// ---------------------------------------------------------------------------
// Kernel 3: MFMA implicit-GEMM conv (per tap: C[o][x] += W[o][ci] * X[ci][x']).
// Block = (sample, 4-row chunk); 4 waves; wave = 1 output row x 64 couts.
// in_s layout: ((r*4+cib)*66 + col)*8 + cj   (col = gx+1, ci = cib*8+cj)
// w_s  layout: ((tap*4+cib)*64 + o )*8 + cj
// ---------------------------------------------------------------------------
__global__ __launch_bounds__(256, 2) void conv_mfma(
    const void* __restrict__ xin,     // [32][64][64][64]
    const u16*  __restrict__ aggw,    // [32][9][64][64] bf16
    const float* __restrict__ aggb,   // [32][64]
    void* __restrict__ out)
{
    __shared__ __align__(16) u16 smem[31104];   // 62208 B: in_s(12672) + w_s(18432); reused as out_s
    __shared__ float bias_s[COUT_];
    __shared__ int s_ok;
    u16* in_s = smem;
    u16* w_s  = smem + 12672;

    const int t    = threadIdx.x;
    const int bz   = blockIdx.x;
    const int b    = bz >> 4;
    const int y0   = (bz & 15) * 4;
    const int wv   = t >> 6;
    const int lane = t & 63, l15 = lane & 15, q = lane >> 4;

    if (t == 0) s_ok = 1;
    __syncthreads();
    if (t < 32) {
        u32 w = ((const u32*)xin)[t * 131072];
        u32 lo = w & 0xFFFFu, ex = (lo >> 7) & 0xFFu;
        if (!(lo == 0u || (ex >= 64u && ex <= 191u))) atomicAnd(&s_ok, 0);
    }
    if (t < COUT_) bias_s[t] = aggb[b * COUT_ + t];
    __syncthreads();
    const int inbf = s_ok;

    floatx4 acc[4][4];
#pragma unroll
    for (int mt = 0; mt < 4; ++mt)
#pragma unroll
        for (int nt = 0; nt < 4; ++nt) acc[mt][nt] = (floatx4)0.f;

    for (int ph = 0; ph < 2; ++ph) {
        const int ci0 = ph * 32;
        __syncthreads();   // protect previous phase's LDS reads
        // ---- stage weights: 9 taps x 4 cib x 64 o, 16B per item
#pragma unroll
        for (int j = 0; j < 9; ++j) {
            const int item = t + 256 * j;
            const int o = item & 63, cib = (item >> 6) & 3, tap = item >> 8;
            uint4 v = *(const uint4*)(aggw + b * 36864 + tap * 4096 + o * 64 + ci0 + cib * 8);
            *(uint4*)&w_s[((tap * 4 + cib) * 64 + o) * 8] = v;
        }
        // ---- stage input (transposed to pixel-major x ci-contiguous)
#pragma unroll
        for (int j = 0; j < 3; ++j) {
            const int item = t + 256 * j;          // 768 items
            const int cp = item & 15, z = item >> 4;
            const int r = z % 6, ch = z / 6;
            const int gy = y0 - 1 + r, gx0 = ch * 8;
            const int ci = ci0 + cp * 2;
            union { uint4 v; u16 s[8]; } a0, a1;
            if (gy >= 0 && gy < HW_) {
                const int gi = ((b * CIN_ + ci) * HW_ + gy) * HW_ + gx0;
                if (inbf) {
                    a0.v = *(const uint4*)((const bf16*)xin + gi);
                    a1.v = *(const uint4*)((const bf16*)xin + gi + HW_ * HW_);
                } else {
                    const float* p0 = (const float*)xin + gi;
                    const float* p1 = p0 + HW_ * HW_;
                    float4 f00 = *(const float4*)p0, f01 = *(const float4*)(p0 + 4);
                    float4 f10 = *(const float4*)p1, f11 = *(const float4*)(p1 + 4);
                    a0.s[0]=f2bu(f00.x); a0.s[1]=f2bu(f00.y); a0.s[2]=f2bu(f00.z); a0.s[3]=f2bu(f00.w);
                    a0.s[4]=f2bu(f01.x); a0.s[5]=f2bu(f01.y); a0.s[6]=f2bu(f01.z); a0.s[7]=f2bu(f01.w);
                    a1.s[0]=f2bu(f10.x); a1.s[1]=f2bu(f10.y); a1.s[2]=f2bu(f10.z); a1.s[3]=f2bu(f10.w);
                    a1.s[4]=f2bu(f11.x); a1.s[5]=f2bu(f11.y); a1.s[6]=f2bu(f11.z); a1.s[7]=f2bu(f11.w);
                }
            } else {
                a0.v = make_uint4(0,0,0,0); a1.v = make_uint4(0,0,0,0);
            }
            const int cib = cp >> 2, p = cp & 3;
            u32* dst = (u32*)in_s;
#pragma unroll
            for (int k = 0; k < 8; ++k) {
                const int col = 1 + gx0 + k;
                dst[((r * 4 + cib) * 66 + col) * 4 + p] = (u32)a0.s[k] | ((u32)a1.s[k] << 16);
            }
        }
        // zero halo columns (gx = -1 and 64)
        if (t < 192) {
            const int cp = t & 15, z = t >> 4;
            const int r = z % 6, col = (z / 6) ? 65 : 0;
            ((u32*)in_s)[((r * 4 + (cp >> 2)) * 66 + col) * 4 + (cp & 3)] = 0u;
        }
        __syncthreads();
        // ---- 9 taps x 16 MFMA tiles
#pragma unroll
        for (int tap = 0; tap < 9; ++tap) {
            const int kh = tap / 3, kw = tap % 3;
            short8 af[4], bfr[4];
#pragma unroll
            for (int mt = 0; mt < 4; ++mt)
                af[mt] = *(const short8*)&w_s[((tap * 4 + q) * 64 + mt * 16 + l15) * 8];
#pragma unroll
            for (int nt = 0; nt < 4; ++nt)
                bfr[nt] = *(const short8*)&in_s[(((wv + kh) * 4 + q) * 66 + nt * 16 + l15 + kw) * 8];
#pragma unroll
            for (int mt = 0; mt < 4; ++mt)
#pragma unroll
                for (int nt = 0; nt < 4; ++nt)
                    acc[mt][nt] = __builtin_amdgcn_mfma_f32_16x16x32_bf16(af[mt], bfr[nt], acc[mt][nt], 0, 0, 0);
        }
    }

    __syncthreads();   // all MFMA LDS reads done; reuse smem as out staging
    u16* out_s = smem; // [wv][o][68]
#pragma unroll
    for (int mt = 0; mt < 4; ++mt) {
        floatx4 bb = *(const floatx4*)&bias_s[mt * 16 + q * 4];
#pragma unroll
        for (int nt = 0; nt < 4; ++nt) {
#pragma unroll
            for (int rg = 0; rg < 4; ++rg) {
                const float v = acc[mt][nt][rg] + bb[rg];
                out_s[(wv * 64 + (mt * 16 + q * 4 + rg)) * 68 + nt * 16 + l15] = f2bu(v);
            }
        }
    }
    __syncthreads();
    const int outbf = inbf;
#pragma unroll
    for (int j = 0; j < 16; ++j) {
        const int c = t + 256 * j;                 // 4096 chunks of 4 elems
        const int x0 = (c & 15) * 4, o = (c >> 4) & 63, w2 = c >> 10;
        const u16* src = &out_s[(w2 * 64 + o) * 68 + x0];
        const u16 h0 = src[0], h1 = src[1], h2 = src[2], h3 = src[3];
        const int gidx = ((b * COUT_ + o) * HW_ + (y0 + w2)) * HW_ + x0;
        if (outbf) {
            uint2 pk; pk.x = (u32)h0 | ((u32)h1 << 16); pk.y = (u32)h2 | ((u32)h3 << 16);
            *(uint2*)((u16*)out + gidx) = pk;
        } else {
            float4 f; f.x = bu2f(h0); f.y = bu2f(h1); f.z = bu2f(h2); f.w = bu2f(h3);
            *(float4*)((float*)out + gidx) = f;
        }
    }
}

// ---------------------------------------------------------------------------
extern "C" void kernel_launch(void* const* d_in, const int* in_sizes, int n_in,
                              void* d_out, int out_size, void* d_ws, size_t ws_size,
                              hipStream_t stream) {
    const void* x      = d_in[0];
    const void* xin    = d_in[1];
    const void* fc1_w  = d_in[2];
    const void* fc1_b  = d_in[3];
    const void* fc2_w  = d_in[4];
    const void* fc2_b  = d_in[5];
    const void* weight = d_in[6];
    const void* bias_p = d_in[7];

    float* ws      = (float*)d_ws;
    float* ws_attn = ws;                    // 256 floats
    float* ws_aggb = ws + 256;              // 2048 floats
    u16*   ws_aggw = (u16*)(ws + 2304);     // 32*9*64*64 bf16 = 2.36 MB

    routing_kernel<<<dim3(B_), dim3(256), 0, stream>>>(
        x, xin, fc1_w, fc1_b, fc2_w, fc2_b, bias_p, ws_attn, ws_aggb, d_out);

    agg_kernel<<<dim3(B_ * 16), dim3(256), 0, stream>>>(weight, ws_attn, ws_aggw);

    conv_mfma<<<dim3(B_ * 16), dim3(256), 0, stream>>>(xin, ws_aggw, ws_aggb, d_out);
}